// Round 14
// baseline (262.923 us; speedup 1.0000x reference)
//
#include <hip/hip_runtime.h>

#define D_ 1024
#define H_ 16
#define DH_ 64
#define S_ 2048
#define B_ 4
#define N_ (B_*S_)    // 8192 tokens
#define M3_ 3072
// SCALE * log2(e): fold into q so softmax uses exp2 directly
#define QSC_ 0.18033688011112042f

typedef _Float16 f16;
typedef _Float16 f16x8 __attribute__((ext_vector_type(8)));
typedef _Float16 f16x4 __attribute__((ext_vector_type(4)));
typedef _Float16 f16x2 __attribute__((ext_vector_type(2)));
typedef __fp16   h16x2 __attribute__((ext_vector_type(2)));
typedef float    f32x4 __attribute__((ext_vector_type(4)));

typedef __attribute__((address_space(1))) void gvoid;
typedef __attribute__((address_space(3))) void lvoid;

__device__ __forceinline__ void gl16(const f16* g, f16* l) {
    __builtin_amdgcn_global_load_lds((gvoid*)g, (lvoid*)l, 16, 0, 0);
}

__device__ __forceinline__ f16x2 pk_cvt(float a, float b) {
#if __has_builtin(__builtin_amdgcn_cvt_pkrtz)
    h16x2 t = __builtin_amdgcn_cvt_pkrtz(a, b);
    return __builtin_bit_cast(f16x2, t);
#else
    f16x2 r; r[0] = (f16)a; r[1] = (f16)b; return r;
#endif
}

// ------------------------------------------------------- fused preprocessing
// blocks [0,8192):       x fp32 -> f16 (1024 elems/block)
// blocks [8192,11264):   w_qkv [1024][3072] -> wqkvT [3072][1024] f16
// blocks [11264,12288):  w_out [1024][1024] -> woutT [1024][1024] f16
__global__ __launch_bounds__(256) void prep_kernel(
        const float* __restrict__ x,  f16* __restrict__ xb,
        const float* __restrict__ wq, f16* __restrict__ wqT,
        const float* __restrict__ wo, f16* __restrict__ woT) {
    __shared__ float tile[32][33];
    const int bid = blockIdx.x;
    if (bid < 8192) {
        size_t i = ((size_t)bid * 256 + threadIdx.x) * 4;
        float4 f = *reinterpret_cast<const float4*>(x + i);
        f16x4 o;
        o[0] = (f16)f.x; o[1] = (f16)f.y; o[2] = (f16)f.z; o[3] = (f16)f.w;
        *reinterpret_cast<f16x4*>(xb + i) = o;
        return;
    }
    const float* in; f16* out; int Nc, bx, by;
    if (bid < 11264) {
        int t = bid - 8192;  in = wq; out = wqT; Nc = M3_;
        bx = t % 96; by = t / 96;
    } else {
        int t = bid - 11264; in = wo; out = woT; Nc = D_;
        bx = t & 31; by = t >> 5;
    }
    int tx = threadIdx.x & 31, ty = threadIdx.x >> 5;
    int c = bx * 32 + tx;
    #pragma unroll
    for (int i = 0; i < 4; i++) {
        int r = by * 32 + ty + i * 8;
        tile[ty + i * 8][tx] = in[(size_t)r * Nc + c];
    }
    __syncthreads();
    #pragma unroll
    for (int i = 0; i < 4; i++) {
        int r2 = bx * 32 + ty + i * 8;   // out row (col of in)
        int c2 = by * 32 + tx;           // out col (row of in)
        out[(size_t)r2 * D_ + c2] = (f16)tile[tx][ty + i * 8];
    }
}

// --------------------------------------------------------------- QKV GEMM
// R14: 256(tokens) x 128(outputs) tile, 512 threads / 8 waves (each 64x64,
// acc[4][4] unchanged), counted-vmcnt TRIPLE buffer kept from R11.
// Mechanism (same as the attn-512 win): each staged B (weight) panel serves
// 2x the token rows -> B staging traffic halves; LDS 72 KB -> 2 blocks/CU x
// 8 waves = 16 waves/CU (up from ~10 at Occupancy 30%) -> more TLP against
// the measured ~50% latency-dead cycles.
// Ledger (3 gl16/thread/K-step): prologue stages tiles 0,1 (6 outstanding),
// waits vmcnt(3); iter kt stages kt+2 (->6), MFMA, waits vmcnt(3) (retires
// kt+1; kt+2 stays in flight ACROSS the barrier); drains 0 only at kt=30.
__global__ __launch_bounds__(512, 2) void gemm_qkv_kernel(
        const f16* __restrict__ A, const f16* __restrict__ Bt,
        const float* __restrict__ bias,
        f16* __restrict__ qo, f16* __restrict__ ko, f16* __restrict__ vTo) {
    __shared__ __align__(16) f16 As[3][256 * 32];   // 16 KB / buf
    __shared__ __align__(16) f16 Bs[3][128 * 32];   //  8 KB / buf
    const int tid  = threadIdx.x;
    const int lane = tid & 63, w = tid >> 6;        // w in 0..7
    const int quad = lane >> 4, lrow = lane & 15;
    const int wn = ((w >> 1) & 3) * 64;             // n-quarter (tokens)
    const int wm = (w & 1) * 64;                    // m-half (outputs)
    // 768 blocks: xcd = id&7; idx in 0..95: idx&3 -> n-panel (4/XCD),
    // idx>>2 -> m-panel (24). n-fastest: B panel reused by 4 adjacent blocks.
    const int id  = blockIdx.x;
    const int xcd = id & 7, idx = id >> 3;
    const int n0 = (xcd * 4 + (idx & 3)) * 256;
    const int m0 = (idx >> 2) * 128;

    f32x4 acc[4][4];
    #pragma unroll
    for (int i = 0; i < 4; i++)
        #pragma unroll
        for (int j = 0; j < 4; j++) acc[i][j] = {0.f, 0.f, 0.f, 0.f};

    // staging: A chunks c0=tid (rows 0..127), c1=tid+512 (rows 128..255);
    // B chunk tid (rows 0..127). row r = c>>2, 16B part p = c&3.
    const int ar0 = tid >> 2, ap0 = tid & 3;
    const f16* Ag0 = A  + (size_t)(n0 + ar0) * D_ + ap0 * 8;
    const f16* Ag1 = Ag0 + (size_t)128 * D_;
    const f16* Bg0 = Bt + (size_t)(m0 + ar0) * D_ + ap0 * 8;

    // prologue: tile0 -> buf0, tile1 -> buf1 (6 outstanding); wait tile0 only.
    gl16(Ag0, &As[0][tid * 8]);
    gl16(Ag1, &As[0][tid * 8 + 128 * 32]);
    gl16(Bg0, &Bs[0][tid * 8]);
    gl16(Ag0 + 32, &As[1][tid * 8]);
    gl16(Ag1 + 32, &As[1][tid * 8 + 128 * 32]);
    gl16(Bg0 + 32, &Bs[1][tid * 8]);
    asm volatile("s_waitcnt vmcnt(3)" ::: "memory");
    __builtin_amdgcn_s_barrier();
    __builtin_amdgcn_sched_barrier(0);

    int cur = 0;
    for (int kt = 0; kt < 32; kt++) {
        // stage tile kt+2 into buf (cur+2)%3 (freed by end-of-(kt-1) barrier)
        if (kt + 2 < 32) {
            int b2 = cur + 2; if (b2 >= 3) b2 -= 3;
            const int ko = (kt + 2) * 32;
            gl16(Ag0 + ko, &As[b2][tid * 8]);
            gl16(Ag1 + ko, &As[b2][tid * 8 + 128 * 32]);
            gl16(Bg0 + ko, &Bs[b2][tid * 8]);
            __builtin_amdgcn_sched_barrier(0);
        }
        f16x8 af[4], bf[4];
        #pragma unroll
        for (int i = 0; i < 4; i++)
            af[i] = *reinterpret_cast<const f16x8*>(&As[cur][(wn + i * 16 + lrow) * 32 + quad * 8]);
        #pragma unroll
        for (int j = 0; j < 4; j++)
            bf[j] = *reinterpret_cast<const f16x8*>(&Bs[cur][(wm + j * 16 + lrow) * 32 + quad * 8]);
        __builtin_amdgcn_s_setprio(1);
        #pragma unroll
        for (int i = 0; i < 4; i++)
            #pragma unroll
            for (int j = 0; j < 4; j++)
                acc[i][j] = __builtin_amdgcn_mfma_f32_16x16x32_f16(af[i], bf[j], acc[i][j], 0, 0, 0);
        __builtin_amdgcn_s_setprio(0);
        // counted wait: retire tile kt+1 (issued a full K-step earlier);
        // tile kt+2 stays in flight across the barrier. Drain only at tail.
        if (kt + 2 < 32) {
            asm volatile("s_waitcnt vmcnt(3)" ::: "memory");
            __builtin_amdgcn_s_barrier();
            __builtin_amdgcn_sched_barrier(0);
        } else if (kt + 1 < 32) {
            asm volatile("s_waitcnt vmcnt(0)" ::: "memory");
            __builtin_amdgcn_s_barrier();
            __builtin_amdgcn_sched_barrier(0);
        }
        cur += 1; if (cur == 3) cur = 0;
    }

    // epilogue: bias + route. q/k: [b][h][s][d]; v: [b][h][d][s] packed x4
    #pragma unroll
    for (int j = 0; j < 4; j++) {
        int m   = m0 + wm + j * 16 + lrow;
        int sec = m >> 10;
        int hd  = m & 1023;
        int hh  = hd >> 6, d = hd & 63;
        float bb = bias[m];
        if (sec == 2) {
            #pragma unroll
            for (int i = 0; i < 4; i++) {
                int n = n0 + wn + i * 16 + quad * 4;   // r=0 element
                int bidx = n >> 11, s = n & 2047;
                f16x4 o;
                #pragma unroll
                for (int r = 0; r < 4; r++) o[r] = (f16)(acc[i][j][r] + bb);
                *reinterpret_cast<f16x4*>(
                    &vTo[(((size_t)(bidx * H_ + hh)) * DH_ + d) * S_ + s]) = o;
            }
        } else {
            f16* dst = (sec == 0) ? qo : ko;
            float sc = (sec == 0) ? QSC_ : 1.0f;
            #pragma unroll
            for (int i = 0; i < 4; i++) {
                #pragma unroll
                for (int r = 0; r < 4; r++) {
                    int n = n0 + wn + i * 16 + quad * 4 + r;
                    int bidx = n >> 11, s = n & 2047;
                    dst[(((size_t)(bidx * H_ + hh)) * S_ + s) * DH_ + d] =
                        (f16)((acc[i][j][r] + bb) * sc);
                }
            }
        }
    }
}

// --------------------------------------------------------------- flash attention
// v7 (kept; R13 win): v6 pipeline at 512 threads / 8 waves / 256 q-rows per
// block (grid 512). Same 16 waves/CU, same 32 KB LDS, same per-wave work —
// staged K/V traffic halves vs v6.
// q,k: [bh][s][64] (q pre-scaled by QSC_); vT: [bh][64][s]; ctx: [b*S][1024] f16
__global__ __launch_bounds__(512, 2) void attn_kernel(
        const f16* __restrict__ q, const f16* __restrict__ k,
        const f16* __restrict__ vT, f16* __restrict__ ctx) {
    __shared__ __align__(16) f16 Ks[2][64 * 64];   // [slot][d], swizzled parts
    __shared__ __align__(16) f16 Vs[2][64 * 64];   // [d][kv],  swizzled parts
    const int tid  = threadIdx.x;
    const int lane = tid & 63, w = tid >> 6;       // w in 0..7
    const int quad = lane >> 4, lrow = lane & 15;
    const int id = blockIdx.x;
    const int bh = id & 63;                  // id%8 == bh%8 -> same XCD per head
    const int q0 = (id >> 6) * 256;          // 256 q rows per block, 32 per wave
    const int b  = bh >> 4, h = bh & 15;
    const f16* qb = q  + (size_t)bh * S_ * DH_;
    const f16* kb = k  + (size_t)bh * S_ * DH_;
    const f16* vb = vT + (size_t)bh * DH_ * S_;

    // Q fragments (B-operand: n=lane&15 -> q, k=quad*8+j -> d); 2 frags/wave
    f16x8 qf[2][2];
    #pragma unroll
    for (int f = 0; f < 2; f++)
        #pragma unroll
        for (int hf = 0; hf < 2; hf++)
            qf[f][hf] = *reinterpret_cast<const f16x8*>(
                qb + (size_t)(q0 + w * 32 + f * 16 + lrow) * DH_ + hf * 32 + quad * 8);

    // ones fragment for l-accumulation MFMA (A[m][k] = 1)
    f16x8 ones8;
    #pragma unroll
    for (int i = 0; i < 8; i++) ones8[i] = (f16)1.f;

    f32x4 lacc[2];    // all 16 C-rows hold the same full kv-sum per q-col
    f32x4 ot[2][4];   // O^T accum: col=lane&15 -> q, row=dj*16+quad*4+r -> d
    #pragma unroll
    for (int f = 0; f < 2; f++) {
        lacc[f] = {0.f, 0.f, 0.f, 0.f};
        #pragma unroll
        for (int dj = 0; dj < 4; dj++) ot[f][dj] = {0.f, 0.f, 0.f, 0.f};
    }

    // K gl16 source offsets: chunk c=tid -> LDS slot s=c>>3, 16B part p=c&7.
    // Stored data = K[ sigma^{-1}(s) ][ (p ^ (s&7))*8 .. +8 ).
    // sigma^{-1}: s -> (s&~31) | (((s>>2)&3)<<3) | (((s>>4)&1)<<2) | (s&3)
    // V: LDS row d=c>>3, part p stores kv-part p^(d&7) of global row d.
    int koff0, voff0;
    {
        int c = tid;
        int s = c >> 3, p = c & 7;
        int g = (s & ~31) | (((s >> 2) & 3) << 3) | (((s >> 4) & 1) << 2) | (s & 3);
        koff0 = g * DH_ + ((p ^ (s & 7)) * 8);
        voff0 = s * S_ + ((p ^ (s & 7)) * 8);   // for V: s is the d-row
    }

    // stage tile 0 into buf 0 (1 K chunk + 1 V chunk per thread)
    gl16(kb + koff0, &Ks[0][tid * 8]);
    gl16(vb + voff0, &Vs[0][tid * 8]);
    __syncthreads();

    // read-side XOR chunk offsets (elements) for K
    const int xr0 = (quad ^ (lrow & 7)) * 8;          // d-part quad
    const int xr1 = ((quad + 4) ^ (lrow & 7)) * 8;    // d-part quad+4

    union PU { f16x8 v; f16x2 w[4]; };

    const int NT = S_ / 64;
    for (int kt = 0; kt < NT; kt++) {
        const int cur = kt & 1;
        const f16* Kc = Ks[cur];
        const f16* Vc = Vs[cur];

        // ---- QK strips 0,1 (t=0)
        f32x4 st0[2][2];
        __builtin_amdgcn_s_setprio(1);
        #pragma unroll
        for (int half = 0; half < 2; half++) {
            const int rb = (half * 16 + lrow) * 64;
            const f16x8 k0 = *reinterpret_cast<const f16x8*>(&Kc[rb + xr0]);
            const f16x8 k1 = *reinterpret_cast<const f16x8*>(&Kc[rb + xr1]);
            #pragma unroll
            for (int f = 0; f < 2; f++) {
                f32x4 s = {0.f, 0.f, 0.f, 0.f};
                s = __builtin_amdgcn_mfma_f32_16x16x32_f16(k0, qf[f][0], s, 0, 0, 0);
                s = __builtin_amdgcn_mfma_f32_16x16x32_f16(k1, qf[f][1], s, 0, 0, 0);
                st0[half][f] = s;
            }
        }
        __builtin_amdgcn_s_setprio(0);

        // ---- issue next tile staging (lands during this tile's compute)
        if (kt + 1 < NT) {
            const size_t kv1 = (size_t)(kt + 1) * 64;
            gl16(kb + kv1 * DH_ + koff0, &Ks[cur ^ 1][tid * 8]);
            gl16(vb + kv1 + voff0,       &Vs[cur ^ 1][tid * 8]);
        }

        // ---- exp + pack t=0
        PU p0[2];
        #pragma unroll
        for (int half = 0; half < 2; half++)
            #pragma unroll
            for (int f = 0; f < 2; f++) {
                f16x2 lo = pk_cvt(__builtin_amdgcn_exp2f(st0[half][f][0]),
                                  __builtin_amdgcn_exp2f(st0[half][f][1]));
                f16x2 hi = pk_cvt(__builtin_amdgcn_exp2f(st0[half][f][2]),
                                  __builtin_amdgcn_exp2f(st0[half][f][3]));
                p0[f].w[half * 2 + 0] = lo;
                p0[f].w[half * 2 + 1] = hi;
            }

        // ---- QK strips 2,3 (t=1) — bridges exp(t0)->PV(t0) dependency gap
        f32x4 st1[2][2];
        __builtin_amdgcn_s_setprio(1);
        #pragma unroll
        for (int half = 0; half < 2; half++) {
            const int rb = ((2 + half) * 16 + lrow) * 64;
            const f16x8 k0 = *reinterpret_cast<const f16x8*>(&Kc[rb + xr0]);
            const f16x8 k1 = *reinterpret_cast<const f16x8*>(&Kc[rb + xr1]);
            #pragma unroll
            for (int f = 0; f < 2; f++) {
                f32x4 s = {0.f, 0.f, 0.f, 0.f};
                s = __builtin_amdgcn_mfma_f32_16x16x32_f16(k0, qf[f][0], s, 0, 0, 0);
                s = __builtin_amdgcn_mfma_f32_16x16x32_f16(k1, qf[f][1], s, 0, 0, 0);
                st1[half][f] = s;
            }
        }
        __builtin_amdgcn_s_setprio(0);

        // ---- V fragments t=0
        f16x8 vf0[4];
        #pragma unroll
        for (int dj = 0; dj < 4; dj++)
            vf0[dj] = *reinterpret_cast<const f16x8*>(
                &Vc[(dj * 16 + lrow) * 64 + ((quad ^ (lrow & 7)) * 8)]);

        // ---- PV t=0 + lacc0
        __builtin_amdgcn_s_setprio(1);
        #pragma unroll
        for (int dj = 0; dj < 4; dj++)
            #pragma unroll
            for (int f = 0; f < 2; f++)
                ot[f][dj] = __builtin_amdgcn_mfma_f32_16x16x32_f16(vf0[dj], p0[f].v, ot[f][dj], 0, 0, 0);
        #pragma unroll
        for (int f = 0; f < 2; f++)
            lacc[f] = __builtin_amdgcn_mfma_f32_16x16x32_f16(ones8, p0[f].v, lacc[f], 0, 0, 0);
        __builtin_amdgcn_s_setprio(0);

        // ---- exp + pack t=1
        PU p1[2];
        #pragma unroll
        for (int half = 0; half < 2; half++)
            #pragma unroll
            for (int f = 0; f < 2; f++) {
                f16x2 lo = pk_cvt(__builtin_amdgcn_exp2f(st1[half][f][0]),
                                  __builtin_amdgcn_exp2f(st1[half][f][1]));
                f16x2 hi = pk_cvt(__builtin_amdgcn_exp2f(st1[half][f][2]),
                                  __builtin_amdgcn_exp2f(st1[half][f][3]));
                p1[f].w[half * 2 + 0] = lo;
                p1[f].w[half * 2 + 1] = hi;
            }

        // ---- V fragments t=1
        f16x8 vf1[4];
        #pragma unroll
        for (int dj = 0; dj < 4; dj++)
            vf1[dj] = *reinterpret_cast<const f16x8*>(
                &Vc[(dj * 16 + lrow) * 64 + (((4 + quad) ^ (lrow & 7)) * 8)]);

        // ---- barrier hoist: all LDS reads of this tile are issued; drain and
        //      barrier NOW, then PV(t1) (pure-register) runs after the barrier,
        //      overlapping the next tile's QK ds_reads of other waves.
        asm volatile("s_waitcnt vmcnt(0) lgkmcnt(0)" ::: "memory");
        __builtin_amdgcn_s_barrier();
        __builtin_amdgcn_sched_barrier(0);

        // ---- PV t=1 + lacc1 (after barrier)
        __builtin_amdgcn_s_setprio(1);
        #pragma unroll
        for (int dj = 0; dj < 4; dj++)
            #pragma unroll
            for (int f = 0; f < 2; f++)
                ot[f][dj] = __builtin_amdgcn_mfma_f32_16x16x32_f16(vf1[dj], p1[f].v, ot[f][dj], 0, 0, 0);
        #pragma unroll
        for (int f = 0; f < 2; f++)
            lacc[f] = __builtin_amdgcn_mfma_f32_16x16x32_f16(ones8, p1[f].v, lacc[f], 0, 0, 0);
        __builtin_amdgcn_s_setprio(0);
    }

    #pragma unroll
    for (int f = 0; f < 2; f++) {
        float inv = 1.0f / lacc[f][0];
        int qrow = q0 + w * 32 + f * 16 + lrow;
        #pragma unroll
        for (int dj = 0; dj < 4; dj++) {
            f16x4 o;
            #pragma unroll
            for (int r = 0; r < 4; r++) o[r] = (f16)(ot[f][dj][r] * inv);
            *reinterpret_cast<f16x4*>(
                &ctx[((size_t)(b * S_ + qrow)) * D_ + h * DH_ + dj * 16 + quad * 4]) = o;
        }
    }
}

// --------------------------------------------------------------- output GEMM
// R12 (kept): counted-vmcnt triple-buffer.
// out[n][m] = sum_k ctx[n][k]*Bt[m][k] + bias[m]   (fp32 out)
__global__ __launch_bounds__(256, 3) void gemm_out_kernel(
        const f16* __restrict__ A, const f16* __restrict__ Bt,
        const float* __restrict__ bias, float* __restrict__ out) {
    __shared__ __align__(16) f16 As[3][128 * 32];
    __shared__ __align__(16) f16 Bs[3][128 * 32];
    const int tid  = threadIdx.x;
    const int lane = tid & 63, w = tid >> 6;
    const int quad = lane >> 4, lrow = lane & 15;
    const int wm = (w & 1) * 64, wn = (w >> 1) * 64;
    const int id  = blockIdx.x;
    const int xcd = id & 7, idx = id >> 3;
    const int n0 = (xcd * 8 + (idx & 7)) * 128;
    const int m0 = (idx >> 3) * 128;

    f32x4 acc[4][4];
    #pragma unroll
    for (int i = 0; i < 4; i++)
        #pragma unroll
        for (int j = 0; j < 4; j++) acc[i][j] = {0.f, 0.f, 0.f, 0.f};

    const int ar0 = tid >> 2, ap0 = tid & 3;
    const f16* Ag0 = A  + (size_t)(n0 + ar0) * D_ + ap0 * 8;
    const f16* Ag1 = Ag0 + (size_t)64 * D_;
    const f16* Bg0 = Bt + (size_t)(m0 + ar0) * D_ + ap0 * 8;
    const f16* Bg1 = Bg0 + (size_t)64 * D_;

    gl16(Ag0, &As[0][tid * 8]);
    gl16(Ag1, &As[0][tid * 8 + 64 * 32]);
    gl16(Bg0, &Bs[0][tid * 8]);
    gl16(Bg1, &Bs[0][tid * 8 + 64 * 32]);
    gl16(Ag0 + 32, &As[1][tid * 8]);
    gl16(Ag1 + 32, &As[1][tid * 8 + 64 * 32]);
    gl16(Bg0 + 32, &Bs[1][tid * 8]);
    gl16(Bg1 + 32, &Bs[1][tid * 8 + 64 * 32]);
    asm volatile("s_waitcnt vmcnt(4)" ::: "memory");
    __builtin_amdgcn_s_barrier();
    __builtin_amdgcn_sched_barrier(0);

    int cur = 0;
    for (int kt = 0; kt < 32; kt++) {
        if (kt + 2 < 32) {
            int b2 = cur + 2; if (b2 >= 3) b2 -= 3;
            const int ko = (kt + 2) * 32;
            gl16(Ag0 + ko, &As[b2][tid * 8]);
            gl16(Ag1 + ko, &As[b2][tid * 8 + 64 * 32]);
            gl16(Bg0 + ko, &Bs[b2][tid * 8]);
            gl16(Bg1 + ko, &Bs[b2][tid * 8 + 64 * 32]);
            __builtin_amdgcn_sched_barrier(0);
        }
        f16x8 af[4], bf[4];
        #pragma unroll
        for (int i = 0; i < 4; i++)
            af[i] = *reinterpret_cast<const f16x8*>(&As[cur][(wm + i * 16 + lrow) * 32 + quad * 8]);
        #pragma unroll
        for (int j = 0; j < 4; j++)
            bf[j] = *reinterpret_cast<const f16x8*>(&Bs[cur][(wn + j * 16 + lrow) * 32 + quad * 8]);
        __builtin_amdgcn_s_setprio(1);
        #pragma unroll
        for (int i = 0; i < 4; i++)
            #pragma unroll
            for (int j = 0; j < 4; j++)
                acc[i][j] = __builtin_amdgcn_mfma_f32_16x16x32_f16(af[i], bf[j], acc[i][j], 0, 0, 0);
        __builtin_amdgcn_s_setprio(0);
        if (kt + 2 < 32) {
            asm volatile("s_waitcnt vmcnt(4)" ::: "memory");
            __builtin_amdgcn_s_barrier();
            __builtin_amdgcn_sched_barrier(0);
        } else if (kt + 1 < 32) {
            asm volatile("s_waitcnt vmcnt(0)" ::: "memory");
            __builtin_amdgcn_s_barrier();
            __builtin_amdgcn_sched_barrier(0);
        }
        cur += 1; if (cur == 3) cur = 0;
    }

    #pragma unroll
    for (int j = 0; j < 4; j++) {
        int m = m0 + wn + j * 16 + lrow;
        float bb = bias[m];
        #pragma unroll
        for (int i = 0; i < 4; i++)
            #pragma unroll
            for (int r = 0; r < 4; r++) {
                int n = n0 + wm + i * 16 + quad * 4 + r;
                out[(size_t)n * D_ + m] = acc[i][j][r] + bb;
            }
    }
}

// ------------------------------------------------------------------- launcher
extern "C" void kernel_launch(void* const* d_in, const int* in_sizes, int n_in,
                              void* d_out, int out_size, void* d_ws, size_t ws_size,
                              hipStream_t stream) {
    (void)in_sizes; (void)n_in; (void)out_size; (void)ws_size;
    const float* x     = (const float*)d_in[0];
    const float* w_qkv = (const float*)d_in[1];
    const float* b_qkv = (const float*)d_in[2];
    const float* w_out = (const float*)d_in[3];
    const float* b_out = (const float*)d_in[4];
    float* out = (float*)d_out;

    char* ws = (char*)d_ws;
    const size_t MB = 1024 * 1024;
    f16* xb    = (f16*)(ws);             // 16 MB  (reused as ctx after GEMM1)
    f16* wqkvT = (f16*)(ws + 16 * MB);   // 6 MB
    f16* woutT = (f16*)(ws + 22 * MB);   // 2 MB
    f16* qs    = (f16*)(ws + 24 * MB);   // 16 MB  [b][h][s][d], pre-scaled
    f16* kk    = (f16*)(ws + 40 * MB);   // 16 MB  [b][h][s][d]
    f16* vTb   = (f16*)(ws + 72 * MB);   // 16 MB  [b][h][d][s]
    f16* ctx   = xb;                     // alias: xb dead after gemm_qkv

    prep_kernel<<<12288, 256, 0, stream>>>(x, xb, w_qkv, wqkvT, w_out, woutT);
    gemm_qkv_kernel<<<(N_ / 256) * (M3_ / 128), 512, 0, stream>>>(xb, wqkvT, b_qkv, qs, kk, vTb);
    attn_kernel<<<(B_ * H_) * (S_ / 256), 512, 0, stream>>>(qs, kk, vTb, ctx);
    gemm_out_kernel<<<512, 256, 0, stream>>>(ctx, woutT, b_out, out);
}

// Round 15
// 253.986 us; speedup vs baseline: 1.0352x; 1.0352x over previous
//
#include <hip/hip_runtime.h>

#define D_ 1024
#define H_ 16
#define DH_ 64
#define S_ 2048
#define B_ 4
#define N_ (B_*S_)    // 8192 tokens
#define M3_ 3072
// SCALE * log2(e): fold into q so softmax uses exp2 directly
#define QSC_ 0.18033688011112042f

typedef _Float16 f16;
typedef _Float16 f16x8 __attribute__((ext_vector_type(8)));
typedef _Float16 f16x4 __attribute__((ext_vector_type(4)));
typedef _Float16 f16x2 __attribute__((ext_vector_type(2)));
typedef __fp16   h16x2 __attribute__((ext_vector_type(2)));
typedef float    f32x4 __attribute__((ext_vector_type(4)));

typedef __attribute__((address_space(1))) void gvoid;
typedef __attribute__((address_space(3))) void lvoid;

__device__ __forceinline__ void gl16(const f16* g, f16* l) {
    __builtin_amdgcn_global_load_lds((gvoid*)g, (lvoid*)l, 16, 0, 0);
}

__device__ __forceinline__ f16x2 pk_cvt(float a, float b) {
#if __has_builtin(__builtin_amdgcn_cvt_pkrtz)
    h16x2 t = __builtin_amdgcn_cvt_pkrtz(a, b);
    return __builtin_bit_cast(f16x2, t);
#else
    f16x2 r; r[0] = (f16)a; r[1] = (f16)b; return r;
#endif
}

// ------------------------------------------------------- fused preprocessing
// blocks [0,8192):       x fp32 -> f16 (1024 elems/block)
// blocks [8192,11264):   w_qkv [1024][3072] -> wqkvT [3072][1024] f16
// blocks [11264,12288):  w_out [1024][1024] -> woutT [1024][1024] f16
__global__ __launch_bounds__(256) void prep_kernel(
        const float* __restrict__ x,  f16* __restrict__ xb,
        const float* __restrict__ wq, f16* __restrict__ wqT,
        const float* __restrict__ wo, f16* __restrict__ woT) {
    __shared__ float tile[32][33];
    const int bid = blockIdx.x;
    if (bid < 8192) {
        size_t i = ((size_t)bid * 256 + threadIdx.x) * 4;
        float4 f = *reinterpret_cast<const float4*>(x + i);
        f16x4 o;
        o[0] = (f16)f.x; o[1] = (f16)f.y; o[2] = (f16)f.z; o[3] = (f16)f.w;
        *reinterpret_cast<f16x4*>(xb + i) = o;
        return;
    }
    const float* in; f16* out; int Nc, bx, by;
    if (bid < 11264) {
        int t = bid - 8192;  in = wq; out = wqT; Nc = M3_;
        bx = t % 96; by = t / 96;
    } else {
        int t = bid - 11264; in = wo; out = woT; Nc = D_;
        bx = t & 31; by = t >> 5;
    }
    int tx = threadIdx.x & 31, ty = threadIdx.x >> 5;
    int c = bx * 32 + tx;
    #pragma unroll
    for (int i = 0; i < 4; i++) {
        int r = by * 32 + ty + i * 8;
        tile[ty + i * 8][tx] = in[(size_t)r * Nc + c];
    }
    __syncthreads();
    #pragma unroll
    for (int i = 0; i < 4; i++) {
        int r2 = bx * 32 + ty + i * 8;   // out row (col of in)
        int c2 = by * 32 + tx;           // out col (row of in)
        out[(size_t)r2 * D_ + c2] = (f16)tile[tx][ty + i * 8];
    }
}

// --------------------------------------------------------------- QKV GEMM
// R11 (reverted to; best of SIX structures tested): 128x128 tile, TRIPLE-
// buffered K-tiles + counted vmcnt at iso-occupancy. Tile kt+2 issued at the
// top of iter kt; end-of-step wait is vmcnt(4) (retires kt+1, leaves kt+2 in
// flight ACROSS the barrier). Drains to 0 only at the tail.
__global__ __launch_bounds__(256, 3) void gemm_qkv_kernel(
        const f16* __restrict__ A, const f16* __restrict__ Bt,
        const float* __restrict__ bias,
        f16* __restrict__ qo, f16* __restrict__ ko, f16* __restrict__ vTo) {
    __shared__ __align__(16) f16 As[3][128 * 32];
    __shared__ __align__(16) f16 Bs[3][128 * 32];
    const int tid  = threadIdx.x;
    const int lane = tid & 63, w = tid >> 6;
    const int quad = lane >> 4, lrow = lane & 15;
    const int wm = (w & 1) * 64, wn = (w >> 1) * 64;
    const int id  = blockIdx.x;
    const int xcd = id & 7, idx = id >> 3;
    const int n0 = (xcd * 8 + (idx & 7)) * 128;
    const int m0 = (idx >> 3) * 128;

    f32x4 acc[4][4];
    #pragma unroll
    for (int i = 0; i < 4; i++)
        #pragma unroll
        for (int j = 0; j < 4; j++) acc[i][j] = {0.f, 0.f, 0.f, 0.f};

    const int ar0 = tid >> 2, ap0 = tid & 3;
    const f16* Ag0 = A  + (size_t)(n0 + ar0) * D_ + ap0 * 8;
    const f16* Ag1 = Ag0 + (size_t)64 * D_;
    const f16* Bg0 = Bt + (size_t)(m0 + ar0) * D_ + ap0 * 8;
    const f16* Bg1 = Bg0 + (size_t)64 * D_;

    gl16(Ag0, &As[0][tid * 8]);
    gl16(Ag1, &As[0][tid * 8 + 64 * 32]);
    gl16(Bg0, &Bs[0][tid * 8]);
    gl16(Bg1, &Bs[0][tid * 8 + 64 * 32]);
    gl16(Ag0 + 32, &As[1][tid * 8]);
    gl16(Ag1 + 32, &As[1][tid * 8 + 64 * 32]);
    gl16(Bg0 + 32, &Bs[1][tid * 8]);
    gl16(Bg1 + 32, &Bs[1][tid * 8 + 64 * 32]);
    asm volatile("s_waitcnt vmcnt(4)" ::: "memory");
    __builtin_amdgcn_s_barrier();
    __builtin_amdgcn_sched_barrier(0);

    int cur = 0;
    for (int kt = 0; kt < 32; kt++) {
        if (kt + 2 < 32) {
            int b2 = cur + 2; if (b2 >= 3) b2 -= 3;
            const int ko = (kt + 2) * 32;
            gl16(Ag0 + ko, &As[b2][tid * 8]);
            gl16(Ag1 + ko, &As[b2][tid * 8 + 64 * 32]);
            gl16(Bg0 + ko, &Bs[b2][tid * 8]);
            gl16(Bg1 + ko, &Bs[b2][tid * 8 + 64 * 32]);
            __builtin_amdgcn_sched_barrier(0);
        }
        f16x8 af[4], bf[4];
        #pragma unroll
        for (int i = 0; i < 4; i++)
            af[i] = *reinterpret_cast<const f16x8*>(&As[cur][(wm + i * 16 + lrow) * 32 + quad * 8]);
        #pragma unroll
        for (int j = 0; j < 4; j++)
            bf[j] = *reinterpret_cast<const f16x8*>(&Bs[cur][(wn + j * 16 + lrow) * 32 + quad * 8]);
        __builtin_amdgcn_s_setprio(1);
        #pragma unroll
        for (int i = 0; i < 4; i++)
            #pragma unroll
            for (int j = 0; j < 4; j++)
                acc[i][j] = __builtin_amdgcn_mfma_f32_16x16x32_f16(af[i], bf[j], acc[i][j], 0, 0, 0);
        __builtin_amdgcn_s_setprio(0);
        if (kt + 2 < 32) {
            asm volatile("s_waitcnt vmcnt(4)" ::: "memory");
            __builtin_amdgcn_s_barrier();
            __builtin_amdgcn_sched_barrier(0);
        } else if (kt + 1 < 32) {
            asm volatile("s_waitcnt vmcnt(0)" ::: "memory");
            __builtin_amdgcn_s_barrier();
            __builtin_amdgcn_sched_barrier(0);
        }
        cur += 1; if (cur == 3) cur = 0;
    }

    // epilogue: bias + route. q/k: [b][h][s][d]; v: [b][h][d][s] packed x4
    #pragma unroll
    for (int j = 0; j < 4; j++) {
        int m   = m0 + wn + j * 16 + lrow;
        int sec = m >> 10;
        int hd  = m & 1023;
        int hh  = hd >> 6, d = hd & 63;
        float bb = bias[m];
        if (sec == 2) {
            #pragma unroll
            for (int i = 0; i < 4; i++) {
                int n = n0 + wm + i * 16 + quad * 4;   // r=0 element
                int bidx = n >> 11, s = n & 2047;
                f16x4 o;
                #pragma unroll
                for (int r = 0; r < 4; r++) o[r] = (f16)(acc[i][j][r] + bb);
                *reinterpret_cast<f16x4*>(
                    &vTo[(((size_t)(bidx * H_ + hh)) * DH_ + d) * S_ + s]) = o;
            }
        } else {
            f16* dst = (sec == 0) ? qo : ko;
            float sc = (sec == 0) ? QSC_ : 1.0f;
            #pragma unroll
            for (int i = 0; i < 4; i++) {
                #pragma unroll
                for (int r = 0; r < 4; r++) {
                    int n = n0 + wm + i * 16 + quad * 4 + r;
                    int bidx = n >> 11, s = n & 2047;
                    dst[(((size_t)(bidx * H_ + hh)) * S_ + s) * DH_ + d] =
                        (f16)((acc[i][j][r] + bb) * sc);
                }
            }
        }
    }
}

// --------------------------------------------------------------- flash attention
// v7 (kept; R13 win): v6 pipeline at 512 threads / 8 waves / 256 q-rows per
// block (grid 512). Same 16 waves/CU, same 32 KB LDS, same per-wave work —
// staged K/V traffic halves vs v6.
// q,k: [bh][s][64] (q pre-scaled by QSC_); vT: [bh][64][s]; ctx: [b*S][1024] f16
__global__ __launch_bounds__(512, 2) void attn_kernel(
        const f16* __restrict__ q, const f16* __restrict__ k,
        const f16* __restrict__ vT, f16* __restrict__ ctx) {
    __shared__ __align__(16) f16 Ks[2][64 * 64];   // [slot][d], swizzled parts
    __shared__ __align__(16) f16 Vs[2][64 * 64];   // [d][kv],  swizzled parts
    const int tid  = threadIdx.x;
    const int lane = tid & 63, w = tid >> 6;       // w in 0..7
    const int quad = lane >> 4, lrow = lane & 15;
    const int id = blockIdx.x;
    const int bh = id & 63;                  // id%8 == bh%8 -> same XCD per head
    const int q0 = (id >> 6) * 256;          // 256 q rows per block, 32 per wave
    const int b  = bh >> 4, h = bh & 15;
    const f16* qb = q  + (size_t)bh * S_ * DH_;
    const f16* kb = k  + (size_t)bh * S_ * DH_;
    const f16* vb = vT + (size_t)bh * DH_ * S_;

    // Q fragments (B-operand: n=lane&15 -> q, k=quad*8+j -> d); 2 frags/wave
    f16x8 qf[2][2];
    #pragma unroll
    for (int f = 0; f < 2; f++)
        #pragma unroll
        for (int hf = 0; hf < 2; hf++)
            qf[f][hf] = *reinterpret_cast<const f16x8*>(
                qb + (size_t)(q0 + w * 32 + f * 16 + lrow) * DH_ + hf * 32 + quad * 8);

    // ones fragment for l-accumulation MFMA (A[m][k] = 1)
    f16x8 ones8;
    #pragma unroll
    for (int i = 0; i < 8; i++) ones8[i] = (f16)1.f;

    f32x4 lacc[2];    // all 16 C-rows hold the same full kv-sum per q-col
    f32x4 ot[2][4];   // O^T accum: col=lane&15 -> q, row=dj*16+quad*4+r -> d
    #pragma unroll
    for (int f = 0; f < 2; f++) {
        lacc[f] = {0.f, 0.f, 0.f, 0.f};
        #pragma unroll
        for (int dj = 0; dj < 4; dj++) ot[f][dj] = {0.f, 0.f, 0.f, 0.f};
    }

    // K gl16 source offsets: chunk c=tid -> LDS slot s=c>>3, 16B part p=c&7.
    // Stored data = K[ sigma^{-1}(s) ][ (p ^ (s&7))*8 .. +8 ).
    // sigma^{-1}: s -> (s&~31) | (((s>>2)&3)<<3) | (((s>>4)&1)<<2) | (s&3)
    // V: LDS row d=c>>3, part p stores kv-part p^(d&7) of global row d.
    int koff0, voff0;
    {
        int c = tid;
        int s = c >> 3, p = c & 7;
        int g = (s & ~31) | (((s >> 2) & 3) << 3) | (((s >> 4) & 1) << 2) | (s & 3);
        koff0 = g * DH_ + ((p ^ (s & 7)) * 8);
        voff0 = s * S_ + ((p ^ (s & 7)) * 8);   // for V: s is the d-row
    }

    // stage tile 0 into buf 0 (1 K chunk + 1 V chunk per thread)
    gl16(kb + koff0, &Ks[0][tid * 8]);
    gl16(vb + voff0, &Vs[0][tid * 8]);
    __syncthreads();

    // read-side XOR chunk offsets (elements) for K
    const int xr0 = (quad ^ (lrow & 7)) * 8;          // d-part quad
    const int xr1 = ((quad + 4) ^ (lrow & 7)) * 8;    // d-part quad+4

    union PU { f16x8 v; f16x2 w[4]; };

    const int NT = S_ / 64;
    for (int kt = 0; kt < NT; kt++) {
        const int cur = kt & 1;
        const f16* Kc = Ks[cur];
        const f16* Vc = Vs[cur];

        // ---- QK strips 0,1 (t=0)
        f32x4 st0[2][2];
        __builtin_amdgcn_s_setprio(1);
        #pragma unroll
        for (int half = 0; half < 2; half++) {
            const int rb = (half * 16 + lrow) * 64;
            const f16x8 k0 = *reinterpret_cast<const f16x8*>(&Kc[rb + xr0]);
            const f16x8 k1 = *reinterpret_cast<const f16x8*>(&Kc[rb + xr1]);
            #pragma unroll
            for (int f = 0; f < 2; f++) {
                f32x4 s = {0.f, 0.f, 0.f, 0.f};
                s = __builtin_amdgcn_mfma_f32_16x16x32_f16(k0, qf[f][0], s, 0, 0, 0);
                s = __builtin_amdgcn_mfma_f32_16x16x32_f16(k1, qf[f][1], s, 0, 0, 0);
                st0[half][f] = s;
            }
        }
        __builtin_amdgcn_s_setprio(0);

        // ---- issue next tile staging (lands during this tile's compute)
        if (kt + 1 < NT) {
            const size_t kv1 = (size_t)(kt + 1) * 64;
            gl16(kb + kv1 * DH_ + koff0, &Ks[cur ^ 1][tid * 8]);
            gl16(vb + kv1 + voff0,       &Vs[cur ^ 1][tid * 8]);
        }

        // ---- exp + pack t=0
        PU p0[2];
        #pragma unroll
        for (int half = 0; half < 2; half++)
            #pragma unroll
            for (int f = 0; f < 2; f++) {
                f16x2 lo = pk_cvt(__builtin_amdgcn_exp2f(st0[half][f][0]),
                                  __builtin_amdgcn_exp2f(st0[half][f][1]));
                f16x2 hi = pk_cvt(__builtin_amdgcn_exp2f(st0[half][f][2]),
                                  __builtin_amdgcn_exp2f(st0[half][f][3]));
                p0[f].w[half * 2 + 0] = lo;
                p0[f].w[half * 2 + 1] = hi;
            }

        // ---- QK strips 2,3 (t=1) — bridges exp(t0)->PV(t0) dependency gap
        f32x4 st1[2][2];
        __builtin_amdgcn_s_setprio(1);
        #pragma unroll
        for (int half = 0; half < 2; half++) {
            const int rb = ((2 + half) * 16 + lrow) * 64;
            const f16x8 k0 = *reinterpret_cast<const f16x8*>(&Kc[rb + xr0]);
            const f16x8 k1 = *reinterpret_cast<const f16x8*>(&Kc[rb + xr1]);
            #pragma unroll
            for (int f = 0; f < 2; f++) {
                f32x4 s = {0.f, 0.f, 0.f, 0.f};
                s = __builtin_amdgcn_mfma_f32_16x16x32_f16(k0, qf[f][0], s, 0, 0, 0);
                s = __builtin_amdgcn_mfma_f32_16x16x32_f16(k1, qf[f][1], s, 0, 0, 0);
                st1[half][f] = s;
            }
        }
        __builtin_amdgcn_s_setprio(0);

        // ---- V fragments t=0
        f16x8 vf0[4];
        #pragma unroll
        for (int dj = 0; dj < 4; dj++)
            vf0[dj] = *reinterpret_cast<const f16x8*>(
                &Vc[(dj * 16 + lrow) * 64 + ((quad ^ (lrow & 7)) * 8)]);

        // ---- PV t=0 + lacc0
        __builtin_amdgcn_s_setprio(1);
        #pragma unroll
        for (int dj = 0; dj < 4; dj++)
            #pragma unroll
            for (int f = 0; f < 2; f++)
                ot[f][dj] = __builtin_amdgcn_mfma_f32_16x16x32_f16(vf0[dj], p0[f].v, ot[f][dj], 0, 0, 0);
        #pragma unroll
        for (int f = 0; f < 2; f++)
            lacc[f] = __builtin_amdgcn_mfma_f32_16x16x32_f16(ones8, p0[f].v, lacc[f], 0, 0, 0);
        __builtin_amdgcn_s_setprio(0);

        // ---- exp + pack t=1
        PU p1[2];
        #pragma unroll
        for (int half = 0; half < 2; half++)
            #pragma unroll
            for (int f = 0; f < 2; f++) {
                f16x2 lo = pk_cvt(__builtin_amdgcn_exp2f(st1[half][f][0]),
                                  __builtin_amdgcn_exp2f(st1[half][f][1]));
                f16x2 hi = pk_cvt(__builtin_amdgcn_exp2f(st1[half][f][2]),
                                  __builtin_amdgcn_exp2f(st1[half][f][3]));
                p1[f].w[half * 2 + 0] = lo;
                p1[f].w[half * 2 + 1] = hi;
            }

        // ---- V fragments t=1
        f16x8 vf1[4];
        #pragma unroll
        for (int dj = 0; dj < 4; dj++)
            vf1[dj] = *reinterpret_cast<const f16x8*>(
                &Vc[(dj * 16 + lrow) * 64 + (((4 + quad) ^ (lrow & 7)) * 8)]);

        // ---- barrier hoist: all LDS reads of this tile are issued; drain and
        //      barrier NOW, then PV(t1) (pure-register) runs after the barrier,
        //      overlapping the next tile's QK ds_reads of other waves.
        asm volatile("s_waitcnt vmcnt(0) lgkmcnt(0)" ::: "memory");
        __builtin_amdgcn_s_barrier();
        __builtin_amdgcn_sched_barrier(0);

        // ---- PV t=1 + lacc1 (after barrier)
        __builtin_amdgcn_s_setprio(1);
        #pragma unroll
        for (int dj = 0; dj < 4; dj++)
            #pragma unroll
            for (int f = 0; f < 2; f++)
                ot[f][dj] = __builtin_amdgcn_mfma_f32_16x16x32_f16(vf1[dj], p1[f].v, ot[f][dj], 0, 0, 0);
        #pragma unroll
        for (int f = 0; f < 2; f++)
            lacc[f] = __builtin_amdgcn_mfma_f32_16x16x32_f16(ones8, p1[f].v, lacc[f], 0, 0, 0);
        __builtin_amdgcn_s_setprio(0);
    }

    #pragma unroll
    for (int f = 0; f < 2; f++) {
        float inv = 1.0f / lacc[f][0];
        int qrow = q0 + w * 32 + f * 16 + lrow;
        #pragma unroll
        for (int dj = 0; dj < 4; dj++) {
            f16x4 o;
            #pragma unroll
            for (int r = 0; r < 4; r++) o[r] = (f16)(ot[f][dj][r] * inv);
            *reinterpret_cast<f16x4*>(
                &ctx[((size_t)(b * S_ + qrow)) * D_ + h * DH_ + dj * 16 + quad * 4]) = o;
        }
    }
}

// --------------------------------------------------------------- output GEMM
// R12 (kept): counted-vmcnt triple-buffer.
// out[n][m] = sum_k ctx[n][k]*Bt[m][k] + bias[m]   (fp32 out)
__global__ __launch_bounds__(256, 3) void gemm_out_kernel(
        const f16* __restrict__ A, const f16* __restrict__ Bt,
        const float* __restrict__ bias, float* __restrict__ out) {
    __shared__ __align__(16) f16 As[3][128 * 32];
    __shared__ __align__(16) f16 Bs[3][128 * 32];
    const int tid  = threadIdx.x;
    const int lane = tid & 63, w = tid >> 6;
    const int quad = lane >> 4, lrow = lane & 15;
    const int wm = (w & 1) * 64, wn = (w >> 1) * 64;
    const int id  = blockIdx.x;
    const int xcd = id & 7, idx = id >> 3;
    const int n0 = (xcd * 8 + (idx & 7)) * 128;
    const int m0 = (idx >> 3) * 128;

    f32x4 acc[4][4];
    #pragma unroll
    for (int i = 0; i < 4; i++)
        #pragma unroll
        for (int j = 0; j < 4; j++) acc[i][j] = {0.f, 0.f, 0.f, 0.f};

    const int ar0 = tid >> 2, ap0 = tid & 3;
    const f16* Ag0 = A  + (size_t)(n0 + ar0) * D_ + ap0 * 8;
    const f16* Ag1 = Ag0 + (size_t)64 * D_;
    const f16* Bg0 = Bt + (size_t)(m0 + ar0) * D_ + ap0 * 8;
    const f16* Bg1 = Bg0 + (size_t)64 * D_;

    gl16(Ag0, &As[0][tid * 8]);
    gl16(Ag1, &As[0][tid * 8 + 64 * 32]);
    gl16(Bg0, &Bs[0][tid * 8]);
    gl16(Bg1, &Bs[0][tid * 8 + 64 * 32]);
    gl16(Ag0 + 32, &As[1][tid * 8]);
    gl16(Ag1 + 32, &As[1][tid * 8 + 64 * 32]);
    gl16(Bg0 + 32, &Bs[1][tid * 8]);
    gl16(Bg1 + 32, &Bs[1][tid * 8 + 64 * 32]);
    asm volatile("s_waitcnt vmcnt(4)" ::: "memory");
    __builtin_amdgcn_s_barrier();
    __builtin_amdgcn_sched_barrier(0);

    int cur = 0;
    for (int kt = 0; kt < 32; kt++) {
        if (kt + 2 < 32) {
            int b2 = cur + 2; if (b2 >= 3) b2 -= 3;
            const int ko = (kt + 2) * 32;
            gl16(Ag0 + ko, &As[b2][tid * 8]);
            gl16(Ag1 + ko, &As[b2][tid * 8 + 64 * 32]);
            gl16(Bg0 + ko, &Bs[b2][tid * 8]);
            gl16(Bg1 + ko, &Bs[b2][tid * 8 + 64 * 32]);
            __builtin_amdgcn_sched_barrier(0);
        }
        f16x8 af[4], bf[4];
        #pragma unroll
        for (int i = 0; i < 4; i++)
            af[i] = *reinterpret_cast<const f16x8*>(&As[cur][(wm + i * 16 + lrow) * 32 + quad * 8]);
        #pragma unroll
        for (int j = 0; j < 4; j++)
            bf[j] = *reinterpret_cast<const f16x8*>(&Bs[cur][(wn + j * 16 + lrow) * 32 + quad * 8]);
        __builtin_amdgcn_s_setprio(1);
        #pragma unroll
        for (int i = 0; i < 4; i++)
            #pragma unroll
            for (int j = 0; j < 4; j++)
                acc[i][j] = __builtin_amdgcn_mfma_f32_16x16x32_f16(af[i], bf[j], acc[i][j], 0, 0, 0);
        __builtin_amdgcn_s_setprio(0);
        if (kt + 2 < 32) {
            asm volatile("s_waitcnt vmcnt(4)" ::: "memory");
            __builtin_amdgcn_s_barrier();
            __builtin_amdgcn_sched_barrier(0);
        } else if (kt + 1 < 32) {
            asm volatile("s_waitcnt vmcnt(0)" ::: "memory");
            __builtin_amdgcn_s_barrier();
            __builtin_amdgcn_sched_barrier(0);
        }
        cur += 1; if (cur == 3) cur = 0;
    }

    #pragma unroll
    for (int j = 0; j < 4; j++) {
        int m = m0 + wn + j * 16 + lrow;
        float bb = bias[m];
        #pragma unroll
        for (int i = 0; i < 4; i++)
            #pragma unroll
            for (int r = 0; r < 4; r++) {
                int n = n0 + wm + i * 16 + quad * 4 + r;
                out[(size_t)n * D_ + m] = acc[i][j][r] + bb;
            }
    }
}

// ------------------------------------------------------------------- launcher
extern "C" void kernel_launch(void* const* d_in, const int* in_sizes, int n_in,
                              void* d_out, int out_size, void* d_ws, size_t ws_size,
                              hipStream_t stream) {
    (void)in_sizes; (void)n_in; (void)out_size; (void)ws_size;
    const float* x     = (const float*)d_in[0];
    const float* w_qkv = (const float*)d_in[1];
    const float* b_qkv = (const float*)d_in[2];
    const float* w_out = (const float*)d_in[3];
    const float* b_out = (const float*)d_in[4];
    float* out = (float*)d_out;

    char* ws = (char*)d_ws;
    const size_t MB = 1024 * 1024;
    f16* xb    = (f16*)(ws);             // 16 MB  (reused as ctx after GEMM1)
    f16* wqkvT = (f16*)(ws + 16 * MB);   // 6 MB
    f16* woutT = (f16*)(ws + 22 * MB);   // 2 MB
    f16* qs    = (f16*)(ws + 24 * MB);   // 16 MB  [b][h][s][d], pre-scaled
    f16* kk    = (f16*)(ws + 40 * MB);   // 16 MB  [b][h][s][d]
    f16* vTb   = (f16*)(ws + 72 * MB);   // 16 MB  [b][h][d][s]
    f16* ctx   = xb;                     // alias: xb dead after gemm_qkv

    prep_kernel<<<12288, 256, 0, stream>>>(x, xb, w_qkv, wqkvT, w_out, woutT);
    gemm_qkv_kernel<<<1536, 256, 0, stream>>>(xb, wqkvT, b_qkv, qs, kk, vTb);
    attn_kernel<<<(B_ * H_) * (S_ / 256), 512, 0, stream>>>(qs, kk, vTb, ctx);
    gemm_out_kernel<<<512, 256, 0, stream>>>(ctx, woutT, b_out, out);
}